// Round 1
// baseline (4514.364 us; speedup 1.0000x reference)
//
#include <hip/hip_runtime.h>
#include <hip/hip_bf16.h>
#include <cstdint>

// ---------- types ----------
typedef __attribute__((ext_vector_type(8))) short bf16x8;          // MFMA A/B frag (8 bf16)
typedef __attribute__((ext_vector_type(8))) unsigned short ushort8;
typedef __attribute__((ext_vector_type(4))) float f32x4;           // MFMA C/D frag

__device__ __forceinline__ unsigned short f2bf(float f) {
    unsigned u = __builtin_bit_cast(unsigned, f);
    u += 0x7FFFu + ((u >> 16) & 1u);     // RNE
    return (unsigned short)(u >> 16);
}
__device__ __forceinline__ float bf2f(unsigned short s) {
    unsigned u = ((unsigned)s) << 16;
    return __builtin_bit_cast(float, u);
}

// async global->LDS DMA, 16B per lane. LDS dest must be wave-uniform base;
// HW writes lane l's 16B to ldsbase + l*16.
__device__ __forceinline__ void gld16(const unsigned short* g, unsigned short* l) {
    __builtin_amdgcn_global_load_lds(
        (const __attribute__((address_space(1))) void*)g,
        (__attribute__((address_space(3))) void*)l, 16, 0, 0);
}

// ---------- f32 -> bf16 weight conversion ----------
__global__ __launch_bounds__(256) void cvt_w(const float* __restrict__ s,
                                             unsigned short* __restrict__ d, int n4) {
    int i = blockIdx.x * 256 + threadIdx.x;
    if (i >= n4) return;
    float4 v = ((const float4*)s)[i];
    ushort4 o = make_ushort4(f2bf(v.x), f2bf(v.y), f2bf(v.z), f2bf(v.w));
    ((ushort4*)d)[i] = o;
}

// ---------- LayerNorm (f32 in) -> bf16 out, one block per row, C=1024 ----------
__global__ __launch_bounds__(256) void ln_bf16(const float* __restrict__ x,
                                               const float* __restrict__ g,
                                               const float* __restrict__ bta,
                                               unsigned short* __restrict__ out) {
    const int row = blockIdx.x;
    const int t = threadIdx.x;
    const float4 v = ((const float4*)(x + (size_t)row * 1024))[t];
    float s  = v.x + v.y + v.z + v.w;
    float ss = v.x*v.x + v.y*v.y + v.z*v.z + v.w*v.w;
#pragma unroll
    for (int off = 32; off > 0; off >>= 1) {
        s  += __shfl_down(s,  off, 64);
        ss += __shfl_down(ss, off, 64);
    }
    __shared__ float red[8];
    if ((t & 63) == 0) { red[t >> 6] = s; red[4 + (t >> 6)] = ss; }
    __syncthreads();
    const float S  = red[0] + red[1] + red[2] + red[3];
    const float SS = red[4] + red[5] + red[6] + red[7];
    const float mu = S * (1.0f / 1024.0f);
    const float rs = rsqrtf(SS * (1.0f / 1024.0f) - mu * mu + 1e-5f);
    const float4 gv = ((const float4*)g)[t];
    const float4 bv = ((const float4*)bta)[t];
    ushort4 o = make_ushort4(f2bf((v.x - mu) * rs * gv.x + bv.x),
                             f2bf((v.y - mu) * rs * gv.y + bv.y),
                             f2bf((v.z - mu) * rs * gv.z + bv.z),
                             f2bf((v.w - mu) * rs * gv.w + bv.w));
    ((ushort4*)(out + (size_t)row * 1024))[t] = o;
}

// ---------- GEMM: C[M,N] = A[M,K](bf16) @ W[N,K](bf16)^T + bias, fused epilogue ----------
// MODE 0: out bf16 = acc + bias
// MODE 1: out f32  = res + acc + bias
// MODE 2: out bf16 = gelu_tanh(acc + bias)
// 128x128 tile, BK=32, 256 threads (4 waves, 2x2), 4x4 MFMA 16x16x32 per wave.
// m97 structure: global_load_lds width-16 staging, 2 barriers per K-step.
// XCD-bijective block swizzle: all col-blocks of a row-panel on one XCD's L2.
template <int MODE>
__global__ __launch_bounds__(256) void gemm_bt(const unsigned short* __restrict__ A,
                                               const unsigned short* __restrict__ W,
                                               const float* __restrict__ bias,
                                               const float* __restrict__ res,
                                               void* __restrict__ outv,
                                               int N, int K) {
    __shared__ __align__(16) unsigned short lA[128 * 32];  // 8 KB
    __shared__ __align__(16) unsigned short lB[128 * 32];  // 8 KB
    const int t = threadIdx.x;
    const int lane = t & 63;
    const int wave = t >> 6;
    const int wm = wave >> 1, wn = wave & 1;

    // T1 XCD swizzle (all grids here have nwg % 8 == 0 -> bijective)
    const int nwg  = gridDim.x * gridDim.y;
    const int orig = blockIdx.y * gridDim.x + blockIdx.x;
    const int id   = (orig & 7) * (nwg >> 3) + (orig >> 3);
    const int bx   = id % gridDim.x;
    const int by   = id / gridDim.x;

    const long row0 = (long)by * 128;
    const long col0 = (long)bx * 128;

    // staging: thread t owns 16B chunk t (rows 0..63) and t+256 (rows 64..127)
    const unsigned short* gA0 = A + (row0 + (t >> 2)) * (long)K + (t & 3) * 8;
    const unsigned short* gA1 = gA0 + 64L * K;
    const unsigned short* gW0 = W + (col0 + (t >> 2)) * (long)K + (t & 3) * 8;
    const unsigned short* gW1 = gW0 + 64L * K;

    // wave-uniform LDS bases; DMA lands lane l at base + l*16B == byte t*16
    unsigned short* lA0w = &lA[wave * 512];
    unsigned short* lA1w = &lA[2048 + wave * 512];
    unsigned short* lB0w = &lB[wave * 512];
    unsigned short* lB1w = &lB[2048 + wave * 512];

    f32x4 acc[4][4] = {};
    const int arow = lane & 15;          // A: m index / B: n index
    const int koff = (lane >> 4) * 8;    // k offset within 32

    for (int kk = 0; kk < K; kk += 32) {
        gld16(gA0 + kk, lA0w);
        gld16(gA1 + kk, lA1w);
        gld16(gW0 + kk, lB0w);
        gld16(gW1 + kk, lB1w);
        __syncthreads();                 // drains vmcnt(0): tile resident
        bf16x8 af[4], bfr[4];
#pragma unroll
        for (int i = 0; i < 4; i++)
            af[i] = *(const bf16x8*)&lA[(wm * 64 + i * 16 + arow) * 32 + koff];
#pragma unroll
        for (int j = 0; j < 4; j++)
            bfr[j] = *(const bf16x8*)&lB[(wn * 64 + j * 16 + arow) * 32 + koff];
#pragma unroll
        for (int i = 0; i < 4; i++)
#pragma unroll
            for (int j = 0; j < 4; j++)
                acc[i][j] = __builtin_amdgcn_mfma_f32_16x16x32_bf16(af[i], bfr[j], acc[i][j], 0, 0, 0);
        __syncthreads();                 // frag reads done before next DMA overwrites
    }

    // epilogue: C/D layout col=lane&15, row=(lane>>4)*4+r
    const int r4 = (lane >> 4) * 4;
#pragma unroll
    for (int j = 0; j < 4; j++) {
        const long col = col0 + wn * 64 + j * 16 + (lane & 15);
        const float bj = bias[col];
#pragma unroll
        for (int i = 0; i < 4; i++) {
#pragma unroll
            for (int r = 0; r < 4; r++) {
                const long row = row0 + wm * 64 + i * 16 + r4 + r;
                float val = acc[i][j][r] + bj;
                if (MODE == 2) {
                    float u = 1.5957691216057308f * (val + 0.044715f * val * val * val); // 2*sqrt(2/pi)*(...)
                    float e = __expf(u);                       // e^{2y}
                    float th = 1.0f - 2.0f / (e + 1.0f);       // tanh(y), NaN-safe
                    val = 0.5f * val * (1.0f + th);
                }
                if (MODE == 1) {
                    ((float*)outv)[row * N + col] = res[row * N + col] + val;
                } else {
                    ((unsigned short*)outv)[row * N + col] = f2bf(val);
                }
            }
        }
    }
}

// ---------- attention: one block per (b,h); N=65, D=64 ----------
// qkv [B*65, 3072] bf16 (q|k|v each 1024 = 16 heads * 64)
// o   [B*65, 1024] bf16
#define SSTR 68  // f32 row stride for q,k (16B-aligned, bank-spread for i-fast access)
__global__ __launch_bounds__(256) void attn(const unsigned short* __restrict__ qkv,
                                            const float* __restrict__ abias,
                                            const float* __restrict__ bscale_p,
                                            unsigned short* __restrict__ o) {
    const int bh = blockIdx.x;
    const int b = bh >> 4, h = bh & 15;
    const int t = threadIdx.x;
    __shared__ __align__(16) float sq[65 * SSTR];           // 17.7 KB
    __shared__ __align__(16) float sk[65 * SSTR];           // 17.7 KB
    __shared__ __align__(16) unsigned short sv[65 * SSTR];  // 8.8 KB (bf16)
    __shared__ float ss[65 * 65];                            // 16.9 KB
    const size_t base = (size_t)b * 65 * 3072 + h * 64;
    for (int idx = t; idx < 65 * 64; idx += 256) {
        int n = idx >> 6, d = idx & 63;
        size_t g = base + (size_t)n * 3072 + d;
        sq[n * SSTR + d] = bf2f(qkv[g]);
        sk[n * SSTR + d] = bf2f(qkv[g + 1024]);
        sv[n * SSTR + d] = qkv[g + 2048];
    }
    __syncthreads();
    const float bs = bscale_p[0];
    const float* bias_h = abias + h * 65 * 65;
    // scores: i-fast so q reads are bank-spread, k reads are wave broadcasts
    for (int p = t; p < 65 * 65; p += 256) {
        int i = p % 65, j = p / 65;
        const float4* q4 = (const float4*)&sq[i * SSTR];
        const float4* k4 = (const float4*)&sk[j * SSTR];
        float ax = 0.f, ay = 0.f, az = 0.f, aw = 0.f;
#pragma unroll
        for (int c = 0; c < 16; c++) {
            float4 a = q4[c], bb = k4[c];
            ax += a.x * bb.x; ay += a.y * bb.y; az += a.z * bb.z; aw += a.w * bb.w;
        }
        ss[i * 65 + j] = (ax + ay + az + aw) * 0.125f + bs * bias_h[i * 65 + j];
    }
    __syncthreads();
    if (t < 65) {  // softmax over j, one row per thread
        float* r = &ss[t * 65];
        float m = -1e30f;
        for (int j = 0; j < 65; j++) m = fmaxf(m, r[j]);
        float sum = 0.f;
        for (int j = 0; j < 65; j++) { float e = __expf(r[j] - m); r[j] = e; sum += e; }
        float inv = 1.0f / sum;
        for (int j = 0; j < 65; j++) r[j] *= inv;
    }
    __syncthreads();
    // o[i][d4*4..+3] : i-fast (ss reads bank-spread, v reads broadcast)
    for (int p = t; p < 65 * 16; p += 256) {
        int i = p % 65, d4 = p / 65;
        float ax = 0.f, ay = 0.f, az = 0.f, aw = 0.f;
        for (int j = 0; j < 65; j++) {
            float pv = ss[i * 65 + j];
            ushort4 vv = *(const ushort4*)&sv[j * SSTR + d4 * 4];
            ax += pv * bf2f(vv.x); ay += pv * bf2f(vv.y);
            az += pv * bf2f(vv.z); aw += pv * bf2f(vv.w);
        }
        size_t go = (size_t)(b * 65 + i) * 1024 + h * 64 + d4 * 4;
        *(ushort4*)&o[go] = make_ushort4(f2bf(ax), f2bf(ay), f2bf(az), f2bf(aw));
    }
}

// ---------- driver ----------
extern "C" void kernel_launch(void* const* d_in, const int* in_sizes, int n_in,
                              void* d_out, int out_size, void* d_ws, size_t ws_size,
                              hipStream_t stream) {
    const float* x      = (const float*)d_in[0];
    const float* ln1_g  = (const float*)d_in[1];
    const float* ln1_b  = (const float*)d_in[2];
    const float* qkv_w  = (const float*)d_in[3];
    const float* qkv_b  = (const float*)d_in[4];
    const float* proj_w = (const float*)d_in[5];
    const float* proj_b = (const float*)d_in[6];
    const float* abias  = (const float*)d_in[7];
    const float* bscale = (const float*)d_in[8];
    const float* ln2_g  = (const float*)d_in[9];
    const float* ln2_b  = (const float*)d_in[10];
    const float* fc1_w  = (const float*)d_in[11];
    const float* fc1_b  = (const float*)d_in[12];
    const float* fc2_w  = (const float*)d_in[13];
    const float* fc2_b  = (const float*)d_in[14];
    float* out = (float*)d_out;

    // workspace layout (bytes):
    //   [0, 545259520)            qkv bf16 [66560,3072] -> reused as h3 bf16 [66560,4096]
    //   [545259520, 681574400)    hbuf bf16 [66560,1024]: h1 -> o -> h2
    //   [681574400, ...)          bf16 weights: qkv_w, proj_w, fc1_w, fc2_w
    char* ws = (char*)d_ws;
    unsigned short* qkvbuf = (unsigned short*)(ws);
    unsigned short* hbuf   = (unsigned short*)(ws + 545259520ULL);
    unsigned short* wqkv   = (unsigned short*)(ws + 681574400ULL);
    unsigned short* wproj  = (unsigned short*)(ws + 687865856ULL);
    unsigned short* wfc1   = (unsigned short*)(ws + 689963008ULL);
    unsigned short* wfc2   = (unsigned short*)(ws + 698351616ULL);

    const int M = 66560;  // B*N = 1024*65, = 520*128

    cvt_w<<<3072, 256, 0, stream>>>(qkv_w,  wqkv,  786432);
    cvt_w<<<1024, 256, 0, stream>>>(proj_w, wproj, 262144);
    cvt_w<<<4096, 256, 0, stream>>>(fc1_w,  wfc1,  1048576);
    cvt_w<<<4096, 256, 0, stream>>>(fc2_w,  wfc2,  1048576);

    ln_bf16<<<M, 256, 0, stream>>>(x, ln1_g, ln1_b, hbuf);                       // h1
    gemm_bt<0><<<dim3(24, 520), 256, 0, stream>>>(hbuf, wqkv, qkv_b, nullptr,
                                                  (void*)qkvbuf, 3072, 1024);    // qkv
    attn<<<16384, 256, 0, stream>>>(qkvbuf, abias, bscale, hbuf);                // o
    gemm_bt<1><<<dim3(8, 520), 256, 0, stream>>>(hbuf, wproj, proj_b, x,
                                                 (void*)out, 1024, 1024);        // x2 = x + proj(o)
    ln_bf16<<<M, 256, 0, stream>>>(out, ln2_g, ln2_b, hbuf);                     // h2
    gemm_bt<2><<<dim3(32, 520), 256, 0, stream>>>(hbuf, wfc1, fc1_b, nullptr,
                                                  (void*)qkvbuf, 4096, 1024);    // h3 = gelu(fc1)
    gemm_bt<1><<<dim3(8, 520), 256, 0, stream>>>(qkvbuf, wfc2, fc2_b, out,
                                                 (void*)out, 1024, 4096);        // out = x2 + fc2(h3)
}

// Round 2
// 3720.128 us; speedup vs baseline: 1.2135x; 1.2135x over previous
//
#include <hip/hip_runtime.h>
#include <hip/hip_bf16.h>
#include <cstdint>

// ---------- types ----------
typedef __attribute__((ext_vector_type(8))) short bf16x8;          // MFMA A/B frag (8 bf16)
typedef __attribute__((ext_vector_type(8))) unsigned short ushort8;
typedef __attribute__((ext_vector_type(4))) float f32x4;           // MFMA C/D frag

__device__ __forceinline__ unsigned short f2bf(float f) {
    unsigned u = __builtin_bit_cast(unsigned, f);
    u += 0x7FFFu + ((u >> 16) & 1u);     // RNE
    return (unsigned short)(u >> 16);
}
__device__ __forceinline__ float bf2f(unsigned short s) {
    unsigned u = ((unsigned)s) << 16;
    return __builtin_bit_cast(float, u);
}

// async global->LDS DMA, 16B per lane. LDS dest is wave-uniform base; lane l lands at base + l*16.
__device__ __forceinline__ void gld16(const unsigned short* g, unsigned short* l) {
    __builtin_amdgcn_global_load_lds(
        (const __attribute__((address_space(1))) void*)g,
        (__attribute__((address_space(3))) void*)l, 16, 0, 0);
}

#define BARRIER    asm volatile("s_barrier" ::: "memory")
#define WAITLGKM0  asm volatile("s_waitcnt lgkmcnt(0)" ::: "memory")
#define WAITVM6    asm volatile("s_waitcnt vmcnt(6)" ::: "memory")

// ---------- f32 -> bf16 weight conversion ----------
__global__ __launch_bounds__(256) void cvt_w(const float* __restrict__ s,
                                             unsigned short* __restrict__ d, int n4) {
    int i = blockIdx.x * 256 + threadIdx.x;
    if (i >= n4) return;
    float4 v = ((const float4*)s)[i];
    ushort4 o = make_ushort4(f2bf(v.x), f2bf(v.y), f2bf(v.z), f2bf(v.w));
    ((ushort4*)d)[i] = o;
}

// ---------- LayerNorm (f32 in) -> bf16 out, one block per row, C=1024 ----------
__global__ __launch_bounds__(256) void ln_bf16(const float* __restrict__ x,
                                               const float* __restrict__ g,
                                               const float* __restrict__ bta,
                                               unsigned short* __restrict__ out) {
    const int row = blockIdx.x;
    const int t = threadIdx.x;
    const float4 v = ((const float4*)(x + (size_t)row * 1024))[t];
    float s  = v.x + v.y + v.z + v.w;
    float ss = v.x*v.x + v.y*v.y + v.z*v.z + v.w*v.w;
#pragma unroll
    for (int off = 32; off > 0; off >>= 1) {
        s  += __shfl_down(s,  off, 64);
        ss += __shfl_down(ss, off, 64);
    }
    __shared__ float red[8];
    if ((t & 63) == 0) { red[t >> 6] = s; red[4 + (t >> 6)] = ss; }
    __syncthreads();
    const float S  = red[0] + red[1] + red[2] + red[3];
    const float SS = red[4] + red[5] + red[6] + red[7];
    const float mu = S * (1.0f / 1024.0f);
    const float rs = rsqrtf(SS * (1.0f / 1024.0f) - mu * mu + 1e-5f);
    const float4 gv = ((const float4*)g)[t];
    const float4 bv = ((const float4*)bta)[t];
    ushort4 o = make_ushort4(f2bf((v.x - mu) * rs * gv.x + bv.x),
                             f2bf((v.y - mu) * rs * gv.y + bv.y),
                             f2bf((v.z - mu) * rs * gv.z + bv.z),
                             f2bf((v.w - mu) * rs * gv.w + bv.w));
    ((ushort4*)(out + (size_t)row * 1024))[t] = o;
}

// ---------- GEMM: C[M,N] = A[M,K](bf16) @ W[N,K](bf16)^T + bias, fused epilogue ----------
// 256x256 tile, BK=64, 512 threads (8 waves, 2Mx4N split-strips), 8-phase schedule
// (T3+T4 counted vmcnt(6) @ phases 4/8, T2 slot-XOR swizzle, T5 setprio, T1 XCD swizzle).
// MODE 0: out bf16 = acc + bias ; MODE 1: out f32 = res + acc + bias ; MODE 2: bf16 gelu(acc+bias)
template <int MODE>
__global__ __launch_bounds__(512, 2) void gemm8p(const unsigned short* __restrict__ A,
                                                 const unsigned short* __restrict__ W,
                                                 const float* __restrict__ bias,
                                                 const float* __restrict__ res,
                                                 void* __restrict__ outv,
                                                 int N, int K) {
    // [slot*2 + half][128 rows * 64 cols] bf16, 16 KB per half-tile; 64 KB per matrix
    __shared__ __align__(128) unsigned short lA[4][8192];
    __shared__ __align__(128) unsigned short lB[4][8192];
    const int t = threadIdx.x;
    const int lane = t & 63;
    const int wave = t >> 6;
    const int wm = wave >> 2, wn = wave & 3;

    // T1 XCD swizzle (all grids have nwg % 8 == 0 -> bijective)
    const int nwg  = gridDim.x * gridDim.y;
    const int orig = blockIdx.y * gridDim.x + blockIdx.x;
    const int id   = (orig & 7) * (nwg >> 3) + (orig >> 3);
    const int bx   = id % gridDim.x;
    const int by   = id / gridDim.x;
    const long row0 = (long)by * 256;
    const long col0 = (long)bx * 256;

    // staging constants: thread covers chunks (wave*128 + q*64 + lane), q=0,1 of each 16KB half.
    // chunk c -> local row c>>3, 16B-slot c&7; source slot pre-swizzled by ^(row&7) so that
    // linear DMA + swizzled ds_read compose to identity (rule #21).
    const int srow  = wave * 16 + (lane >> 3);
    const int sslot = (lane & 7) ^ ((lane >> 3) & 7);
    const unsigned short* gA = A + (row0 + srow) * (long)K + sslot * 8;
    const unsigned short* gW = W + (col0 + srow) * (long)K + sslot * 8;
    const int lwo = wave * 1024;   // ushort offset of this wave's chunk block within a half

#define STG_A(H, TILE, SLOT) do { \
    const unsigned short* _g = gA + (long)(H) * 128 * K + (long)(TILE) * 64; \
    unsigned short* _l = &lA[(SLOT) * 2 + (H)][lwo]; \
    gld16(_g, _l); gld16(_g + 8L * K, _l + 512); } while (0)
#define STG_B(H, TILE, SLOT) do { \
    const unsigned short* _g = gW + (long)(H) * 128 * K + (long)(TILE) * 64; \
    unsigned short* _l = &lB[(SLOT) * 2 + (H)][lwo]; \
    gld16(_g, _l); gld16(_g + 8L * K, _l + 512); } while (0)

    const int NT = K >> 6;    // K/64 K-tiles (even)
    const int I  = NT >> 1;   // main-loop iterations (2 K-tiles each)

    // fragment-read constants. pslot = kslot ^ (row&7); row&7 == lane&7 for all frags.
    const int arow = lane & 15;
    const int khi  = lane >> 4;
    const int low7 = lane & 7;

    f32x4 acc[8][4] = {};     // [mh*4+fi][nh*2+fj]
    bf16x8 af[4][2], bf0[2][2], bf1[2][2];

    // ---- prologue: tile0 {A-h0,B-h0,B-h1,A-h1} + tile1 {A-h0,B-h0,B-h1}; A1-h1 staged at iter0-Pa
    STG_A(0, 0, 0); STG_B(0, 0, 0); STG_B(1, 0, 0); STG_A(1, 0, 0);
    STG_A(0, 1, 1); STG_B(0, 1, 1); STG_B(1, 1, 1);
    WAITVM6;        // oldest 8 loads (= tile0 complete) landed
    BARRIER;

    for (int j = 0; j < I; ++j) {
        const bool stN = (j + 1) < I;
#pragma unroll
        for (int tp = 0; tp < 2; ++tp) {
            const int s2 = tp * 2;
            const int tN = 2 * j + 2 + tp;
            const bool stA1 = (2 * j + tp + 1) < NT;

            // ---- Pa: read af strip0 (A half0) + bf strip0 (B half0); stage A-h1 of tile 2j+tp+1
#pragma unroll
            for (int fi = 0; fi < 4; ++fi) {
                const int r = wm * 64 + fi * 16 + arow;
#pragma unroll
                for (int ks = 0; ks < 2; ++ks)
                    af[fi][ks] = *(const bf16x8*)&lA[s2][r * 64 + (((ks * 4 + khi) ^ low7) << 3)];
            }
#pragma unroll
            for (int fj = 0; fj < 2; ++fj) {
                const int r = wn * 32 + fj * 16 + arow;
#pragma unroll
                for (int ks = 0; ks < 2; ++ks)
                    bf0[fj][ks] = *(const bf16x8*)&lB[s2][r * 64 + (((ks * 4 + khi) ^ low7) << 3)];
            }
            if (stA1) STG_A(1, 2 * j + tp + 1, tp ^ 1);
            BARRIER;
            __builtin_amdgcn_s_setprio(1);
#pragma unroll
            for (int fi = 0; fi < 4; ++fi)
#pragma unroll
                for (int fj = 0; fj < 2; ++fj)
#pragma unroll
                    for (int ks = 0; ks < 2; ++ks)
                        acc[fi][fj] = __builtin_amdgcn_mfma_f32_16x16x32_bf16(af[fi][ks], bf0[fj][ks], acc[fi][fj], 0, 0, 0);
            __builtin_amdgcn_s_setprio(0);
            WAITLGKM0;   // my ds_reads drained before anyone overwrites (next phases' stages)
            BARRIER;

            // ---- Pb: read bf strip1 (B half1); stage A-h0 of tile tN
#pragma unroll
            for (int fj = 0; fj < 2; ++fj) {
                const int r = wn * 32 + fj * 16 + arow;
#pragma unroll
                for (int ks = 0; ks < 2; ++ks)
                    bf1[fj][ks] = *(const bf16x8*)&lB[s2 + 1][r * 64 + (((ks * 4 + khi) ^ low7) << 3)];
            }
            if (stN) STG_A(0, tN, tp);
            BARRIER;
            __builtin_amdgcn_s_setprio(1);
#pragma unroll
            for (int fi = 0; fi < 4; ++fi)
#pragma unroll
                for (int fj = 0; fj < 2; ++fj)
#pragma unroll
                    for (int ks = 0; ks < 2; ++ks)
                        acc[fi][2 + fj] = __builtin_amdgcn_mfma_f32_16x16x32_bf16(af[fi][ks], bf1[fj][ks], acc[fi][2 + fj], 0, 0, 0);
            __builtin_amdgcn_s_setprio(0);
            WAITLGKM0;
            BARRIER;

            // ---- Pc: read af strip1 (A half1); stage B-h0 of tile tN
#pragma unroll
            for (int fi = 0; fi < 4; ++fi) {
                const int r = wm * 64 + fi * 16 + arow;
#pragma unroll
                for (int ks = 0; ks < 2; ++ks)
                    af[fi][ks] = *(const bf16x8*)&lA[s2 + 1][r * 64 + (((ks * 4 + khi) ^ low7) << 3)];
            }
            if (stN) STG_B(0, tN, tp);
            BARRIER;
            __builtin_amdgcn_s_setprio(1);
#pragma unroll
            for (int fi = 0; fi < 4; ++fi)
#pragma unroll
                for (int fj = 0; fj < 2; ++fj)
#pragma unroll
                    for (int ks = 0; ks < 2; ++ks)
                        acc[4 + fi][2 + fj] = __builtin_amdgcn_mfma_f32_16x16x32_bf16(af[fi][ks], bf1[fj][ks], acc[4 + fi][2 + fj], 0, 0, 0);
            __builtin_amdgcn_s_setprio(0);
            WAITLGKM0;
            BARRIER;

            // ---- Pd: no reads (bf0 live); stage B-h1 of tile tN; counted vmcnt
            if (stN) STG_B(1, tN, tp);
            BARRIER;
            __builtin_amdgcn_s_setprio(1);
#pragma unroll
            for (int fi = 0; fi < 4; ++fi)
#pragma unroll
                for (int fj = 0; fj < 2; ++fj)
#pragma unroll
                    for (int ks = 0; ks < 2; ++ks)
                        acc[4 + fi][fj] = __builtin_amdgcn_mfma_f32_16x16x32_bf16(af[fi][ks], bf0[fj][ks], acc[4 + fi][fj], 0, 0, 0);
            __builtin_amdgcn_s_setprio(0);
            WAITVM6;     // all but newest 3 half-tiles landed (phases 4 & 8 only)
            WAITLGKM0;
            BARRIER;
        }
    }

    // ---- epilogue: C/D layout col=lane&15, row=(lane>>4)*4+r ----
    const int r4 = khi * 4;
#pragma unroll
    for (int jj = 0; jj < 4; ++jj) {
        const long col = col0 + (jj >> 1) * 128 + wn * 32 + (jj & 1) * 16 + arow;
        const float bj = bias[col];
#pragma unroll
        for (int i = 0; i < 8; ++i) {
            const long rowb = row0 + (i >> 2) * 128 + wm * 64 + (i & 3) * 16 + r4;
#pragma unroll
            for (int r = 0; r < 4; ++r) {
                const long row = rowb + r;
                float val = acc[i][jj][r] + bj;
                if (MODE == 2) {
                    float u = 1.5957691216057308f * (val + 0.044715f * val * val * val);
                    float e = __expf(u);
                    float th = 1.0f - 2.0f / (e + 1.0f);
                    val = 0.5f * val * (1.0f + th);
                }
                if (MODE == 1) {
                    ((float*)outv)[row * N + col] = res[row * N + col] + val;
                } else {
                    ((unsigned short*)outv)[row * N + col] = f2bf(val);
                }
            }
        }
    }
#undef STG_A
#undef STG_B
}

// ---------- attention: one block per (b,h); N=65, D=64 ----------
#define SSTR 68
__global__ __launch_bounds__(256) void attn(const unsigned short* __restrict__ qkv,
                                            const float* __restrict__ abias,
                                            const float* __restrict__ bscale_p,
                                            unsigned short* __restrict__ o) {
    const int bh = blockIdx.x;
    const int b = bh >> 4, h = bh & 15;
    const int t = threadIdx.x;
    __shared__ __align__(16) float sq[65 * SSTR];
    __shared__ __align__(16) float sk[65 * SSTR];
    __shared__ __align__(16) unsigned short sv[65 * SSTR];
    __shared__ float ss[65 * 65];
    const size_t base = (size_t)b * 65 * 3072 + h * 64;
    for (int idx = t; idx < 65 * 64; idx += 256) {
        int n = idx >> 6, d = idx & 63;
        size_t g = base + (size_t)n * 3072 + d;
        sq[n * SSTR + d] = bf2f(qkv[g]);
        sk[n * SSTR + d] = bf2f(qkv[g + 1024]);
        sv[n * SSTR + d] = qkv[g + 2048];
    }
    __syncthreads();
    const float bs = bscale_p[0];
    const float* bias_h = abias + h * 65 * 65;
    for (int p = t; p < 65 * 65; p += 256) {
        int i = p % 65, j = p / 65;
        const float4* q4 = (const float4*)&sq[i * SSTR];
        const float4* k4 = (const float4*)&sk[j * SSTR];
        float ax = 0.f, ay = 0.f, az = 0.f, aw = 0.f;
#pragma unroll
        for (int c = 0; c < 16; c++) {
            float4 a = q4[c], bb = k4[c];
            ax += a.x * bb.x; ay += a.y * bb.y; az += a.z * bb.z; aw += a.w * bb.w;
        }
        ss[i * 65 + j] = (ax + ay + az + aw) * 0.125f + bs * bias_h[i * 65 + j];
    }
    __syncthreads();
    if (t < 65) {
        float* r = &ss[t * 65];
        float m = -1e30f;
        for (int j = 0; j < 65; j++) m = fmaxf(m, r[j]);
        float sum = 0.f;
        for (int j = 0; j < 65; j++) { float e = __expf(r[j] - m); r[j] = e; sum += e; }
        float inv = 1.0f / sum;
        for (int j = 0; j < 65; j++) r[j] *= inv;
    }
    __syncthreads();
    for (int p = t; p < 65 * 16; p += 256) {
        int i = p % 65, d4 = p / 65;
        float ax = 0.f, ay = 0.f, az = 0.f, aw = 0.f;
        for (int j = 0; j < 65; j++) {
            float pv = ss[i * 65 + j];
            ushort4 vv = *(const ushort4*)&sv[j * SSTR + d4 * 4];
            ax += pv * bf2f(vv.x); ay += pv * bf2f(vv.y);
            az += pv * bf2f(vv.z); aw += pv * bf2f(vv.w);
        }
        size_t go = (size_t)(b * 65 + i) * 1024 + h * 64 + d4 * 4;
        *(ushort4*)&o[go] = make_ushort4(f2bf(ax), f2bf(ay), f2bf(az), f2bf(aw));
    }
}

// ---------- driver ----------
extern "C" void kernel_launch(void* const* d_in, const int* in_sizes, int n_in,
                              void* d_out, int out_size, void* d_ws, size_t ws_size,
                              hipStream_t stream) {
    const float* x      = (const float*)d_in[0];
    const float* ln1_g  = (const float*)d_in[1];
    const float* ln1_b  = (const float*)d_in[2];
    const float* qkv_w  = (const float*)d_in[3];
    const float* qkv_b  = (const float*)d_in[4];
    const float* proj_w = (const float*)d_in[5];
    const float* proj_b = (const float*)d_in[6];
    const float* abias  = (const float*)d_in[7];
    const float* bscale = (const float*)d_in[8];
    const float* ln2_g  = (const float*)d_in[9];
    const float* ln2_b  = (const float*)d_in[10];
    const float* fc1_w  = (const float*)d_in[11];
    const float* fc1_b  = (const float*)d_in[12];
    const float* fc2_w  = (const float*)d_in[13];
    const float* fc2_b  = (const float*)d_in[14];
    float* out = (float*)d_out;

    char* ws = (char*)d_ws;
    unsigned short* qkvbuf = (unsigned short*)(ws);
    unsigned short* hbuf   = (unsigned short*)(ws + 545259520ULL);
    unsigned short* wqkv   = (unsigned short*)(ws + 681574400ULL);
    unsigned short* wproj  = (unsigned short*)(ws + 687865856ULL);
    unsigned short* wfc1   = (unsigned short*)(ws + 689963008ULL);
    unsigned short* wfc2   = (unsigned short*)(ws + 698351616ULL);

    const int M = 66560;  // B*N = 1024*65 = 260*256

    cvt_w<<<3072, 256, 0, stream>>>(qkv_w,  wqkv,  786432);
    cvt_w<<<1024, 256, 0, stream>>>(proj_w, wproj, 262144);
    cvt_w<<<4096, 256, 0, stream>>>(fc1_w,  wfc1,  1048576);
    cvt_w<<<4096, 256, 0, stream>>>(fc2_w,  wfc2,  1048576);

    ln_bf16<<<M, 256, 0, stream>>>(x, ln1_g, ln1_b, hbuf);                        // h1
    gemm8p<0><<<dim3(12, 260), 512, 0, stream>>>(hbuf, wqkv, qkv_b, nullptr,
                                                 (void*)qkvbuf, 3072, 1024);      // qkv
    attn<<<16384, 256, 0, stream>>>(qkvbuf, abias, bscale, hbuf);                 // o
    gemm8p<1><<<dim3(4, 260), 512, 0, stream>>>(hbuf, wproj, proj_b, x,
                                                (void*)out, 1024, 1024);          // x2 = x + proj(o)
    ln_bf16<<<M, 256, 0, stream>>>(out, ln2_g, ln2_b, hbuf);                      // h2
    gemm8p<2><<<dim3(16, 260), 512, 0, stream>>>(hbuf, wfc1, fc1_b, nullptr,
                                                 (void*)qkvbuf, 4096, 1024);      // h3 = gelu(fc1)
    gemm8p<1><<<dim3(4, 260), 512, 0, stream>>>(qkvbuf, wfc2, fc2_b, out,
                                                (void*)out, 1024, 4096);          // out = x2 + fc2(h3)
}

// Round 4
// 3078.189 us; speedup vs baseline: 1.4666x; 1.2085x over previous
//
#include <hip/hip_runtime.h>
#include <hip/hip_bf16.h>
#include <cstdint>

// ---------- types ----------
typedef __attribute__((ext_vector_type(8))) short bf16x8;          // MFMA A/B frag (8 bf16)
typedef __attribute__((ext_vector_type(8))) unsigned short ushort8;
typedef __attribute__((ext_vector_type(4))) float f32x4;           // MFMA C/D frag

__device__ __forceinline__ unsigned short f2bf(float f) {
    unsigned u = __builtin_bit_cast(unsigned, f);
    u += 0x7FFFu + ((u >> 16) & 1u);     // RNE
    return (unsigned short)(u >> 16);
}
__device__ __forceinline__ float bf2f(unsigned short s) {
    unsigned u = ((unsigned)s) << 16;
    return __builtin_bit_cast(float, u);
}

// async global->LDS DMA, 16B per lane. LDS dest is wave-uniform base; lane l lands at base + l*16.
__device__ __forceinline__ void gld16(const unsigned short* g, unsigned short* l) {
    __builtin_amdgcn_global_load_lds(
        (const __attribute__((address_space(1))) void*)g,
        (__attribute__((address_space(3))) void*)l, 16, 0, 0);
}

#define BARRIER    asm volatile("s_barrier" ::: "memory")
#define WAITLGKM0  asm volatile("s_waitcnt lgkmcnt(0)" ::: "memory")
#define WAITVM6    asm volatile("s_waitcnt vmcnt(6)" ::: "memory")

// ---------- f32 -> bf16 weight conversion ----------
__global__ __launch_bounds__(256) void cvt_w(const float* __restrict__ s,
                                             unsigned short* __restrict__ d, int n4) {
    int i = blockIdx.x * 256 + threadIdx.x;
    if (i >= n4) return;
    float4 v = ((const float4*)s)[i];
    ushort4 o = make_ushort4(f2bf(v.x), f2bf(v.y), f2bf(v.z), f2bf(v.w));
    ((ushort4*)d)[i] = o;
}

// ---------- LayerNorm (f32 in) -> bf16 out, one block per row, C=1024 ----------
__global__ __launch_bounds__(256) void ln_bf16(const float* __restrict__ x,
                                               const float* __restrict__ g,
                                               const float* __restrict__ bta,
                                               unsigned short* __restrict__ out) {
    const int row = blockIdx.x;
    const int t = threadIdx.x;
    const float4 v = ((const float4*)(x + (size_t)row * 1024))[t];
    float s  = v.x + v.y + v.z + v.w;
    float ss = v.x*v.x + v.y*v.y + v.z*v.z + v.w*v.w;
#pragma unroll
    for (int off = 32; off > 0; off >>= 1) {
        s  += __shfl_down(s,  off, 64);
        ss += __shfl_down(ss, off, 64);
    }
    __shared__ float red[8];
    if ((t & 63) == 0) { red[t >> 6] = s; red[4 + (t >> 6)] = ss; }
    __syncthreads();
    const float S  = red[0] + red[1] + red[2] + red[3];
    const float SS = red[4] + red[5] + red[6] + red[7];
    const float mu = S * (1.0f / 1024.0f);
    const float rs = rsqrtf(SS * (1.0f / 1024.0f) - mu * mu + 1e-5f);
    const float4 gv = ((const float4*)g)[t];
    const float4 bv = ((const float4*)bta)[t];
    ushort4 o = make_ushort4(f2bf((v.x - mu) * rs * gv.x + bv.x),
                             f2bf((v.y - mu) * rs * gv.y + bv.y),
                             f2bf((v.z - mu) * rs * gv.z + bv.z),
                             f2bf((v.w - mu) * rs * gv.w + bv.w));
    ((ushort4*)(out + (size_t)row * 1024))[t] = o;
}

// ---------- GEMM: C[M,N] = A[M,K](bf16) @ W[N,K](bf16)^T + bias, fused epilogue ----------
// 256x256 tile, BK=64, 512 threads (8 waves, 2Mx4N split-strips), 8-phase schedule
// (T3+T4 counted vmcnt(6) @ phases 4/8, T2 slot-XOR swizzle, T5 setprio, T1 XCD swizzle).
// MODE 0: out bf16 = acc + bias ; MODE 1: out f32 = res + acc + bias ; MODE 2: bf16 gelu(acc+bias)
template <int MODE>
__global__ __launch_bounds__(512, 2) void gemm8p(const unsigned short* __restrict__ A,
                                                 const unsigned short* __restrict__ W,
                                                 const float* __restrict__ bias,
                                                 const float* __restrict__ res,
                                                 void* __restrict__ outv,
                                                 int N, int K) {
    // [slot*2 + half][128 rows * 64 cols] bf16, 16 KB per half-tile; 64 KB per matrix
    __shared__ __align__(128) unsigned short lA[4][8192];
    __shared__ __align__(128) unsigned short lB[4][8192];
    const int t = threadIdx.x;
    const int lane = t & 63;
    const int wave = t >> 6;
    const int wm = wave >> 2, wn = wave & 3;

    // T1 XCD swizzle (all grids have nwg % 8 == 0 -> bijective)
    const int nwg  = gridDim.x * gridDim.y;
    const int orig = blockIdx.y * gridDim.x + blockIdx.x;
    const int id   = (orig & 7) * (nwg >> 3) + (orig >> 3);
    const int bx   = id % gridDim.x;
    const int by   = id / gridDim.x;
    const long row0 = (long)by * 256;
    const long col0 = (long)bx * 256;

    // staging constants: thread covers chunks (wave*128 + q*64 + lane), q=0,1 of each 16KB half.
    // chunk c -> local row c>>3, 16B-slot c&7; source slot pre-swizzled by ^(row&7) so that
    // linear DMA + swizzled ds_read compose to identity (rule #21).
    const int srow  = wave * 16 + (lane >> 3);
    const int sslot = (lane & 7) ^ ((lane >> 3) & 7);
    const unsigned short* gA = A + (row0 + srow) * (long)K + sslot * 8;
    const unsigned short* gW = W + (col0 + srow) * (long)K + sslot * 8;
    const int lwo = wave * 1024;   // ushort offset of this wave's chunk block within a half

#define STG_A(H, TILE, SLOT) do { \
    const unsigned short* _g = gA + (long)(H) * 128 * K + (long)(TILE) * 64; \
    unsigned short* _l = &lA[(SLOT) * 2 + (H)][lwo]; \
    gld16(_g, _l); gld16(_g + 8L * K, _l + 512); } while (0)
#define STG_B(H, TILE, SLOT) do { \
    const unsigned short* _g = gW + (long)(H) * 128 * K + (long)(TILE) * 64; \
    unsigned short* _l = &lB[(SLOT) * 2 + (H)][lwo]; \
    gld16(_g, _l); gld16(_g + 8L * K, _l + 512); } while (0)

    const int NT = K >> 6;    // K/64 K-tiles (even)
    const int I  = NT >> 1;   // main-loop iterations (2 K-tiles each)

    // fragment-read constants. pslot = kslot ^ (row&7); row&7 == lane&7 for all frags.
    const int arow = lane & 15;
    const int khi  = lane >> 4;
    const int low7 = lane & 7;

    f32x4 acc[8][4] = {};     // [mh*4+fi][nh*2+fj]
    bf16x8 af[4][2], bf0[2][2], bf1[2][2];

    // ---- prologue: tile0 {A-h0,B-h0,B-h1,A-h1} + tile1 {A-h0,B-h0,B-h1}; A1-h1 staged at iter0-Pa
    STG_A(0, 0, 0); STG_B(0, 0, 0); STG_B(1, 0, 0); STG_A(1, 0, 0);
    STG_A(0, 1, 1); STG_B(0, 1, 1); STG_B(1, 1, 1);
    WAITVM6;        // oldest 8 loads (= tile0 complete) landed
    BARRIER;

    for (int j = 0; j < I; ++j) {
        const bool stN = (j + 1) < I;
#pragma unroll
        for (int tp = 0; tp < 2; ++tp) {
            const int s2 = tp * 2;
            const int tN = 2 * j + 2 + tp;
            const bool stA1 = (2 * j + tp + 1) < NT;

            // ---- Pa: read af strip0 (A half0) + bf strip0 (B half0); stage A-h1 of tile 2j+tp+1
#pragma unroll
            for (int fi = 0; fi < 4; ++fi) {
                const int r = wm * 64 + fi * 16 + arow;
#pragma unroll
                for (int ks = 0; ks < 2; ++ks)
                    af[fi][ks] = *(const bf16x8*)&lA[s2][r * 64 + (((ks * 4 + khi) ^ low7) << 3)];
            }
#pragma unroll
            for (int fj = 0; fj < 2; ++fj) {
                const int r = wn * 32 + fj * 16 + arow;
#pragma unroll
                for (int ks = 0; ks < 2; ++ks)
                    bf0[fj][ks] = *(const bf16x8*)&lB[s2][r * 64 + (((ks * 4 + khi) ^ low7) << 3)];
            }
            if (stA1) STG_A(1, 2 * j + tp + 1, tp ^ 1);
            BARRIER;
            __builtin_amdgcn_s_setprio(1);
#pragma unroll
            for (int fi = 0; fi < 4; ++fi)
#pragma unroll
                for (int fj = 0; fj < 2; ++fj)
#pragma unroll
                    for (int ks = 0; ks < 2; ++ks)
                        acc[fi][fj] = __builtin_amdgcn_mfma_f32_16x16x32_bf16(af[fi][ks], bf0[fj][ks], acc[fi][fj], 0, 0, 0);
            __builtin_amdgcn_s_setprio(0);
            WAITLGKM0;   // my ds_reads drained before anyone overwrites (next phases' stages)
            BARRIER;

            // ---- Pb: read bf strip1 (B half1); stage A-h0 of tile tN
#pragma unroll
            for (int fj = 0; fj < 2; ++fj) {
                const int r = wn * 32 + fj * 16 + arow;
#pragma unroll
                for (int ks = 0; ks < 2; ++ks)
                    bf1[fj][ks] = *(const bf16x8*)&lB[s2 + 1][r * 64 + (((ks * 4 + khi) ^ low7) << 3)];
            }
            if (stN) STG_A(0, tN, tp);
            BARRIER;
            __builtin_amdgcn_s_setprio(1);
#pragma unroll
            for (int fi = 0; fi < 4; ++fi)
#pragma unroll
                for (int fj = 0; fj < 2; ++fj)
#pragma unroll
                    for (int ks = 0; ks < 2; ++ks)
                        acc[fi][2 + fj] = __builtin_amdgcn_mfma_f32_16x16x32_bf16(af[fi][ks], bf1[fj][ks], acc[fi][2 + fj], 0, 0, 0);
            __builtin_amdgcn_s_setprio(0);
            WAITLGKM0;
            BARRIER;

            // ---- Pc: read af strip1 (A half1); stage B-h0 of tile tN
#pragma unroll
            for (int fi = 0; fi < 4; ++fi) {
                const int r = wm * 64 + fi * 16 + arow;
#pragma unroll
                for (int ks = 0; ks < 2; ++ks)
                    af[fi][ks] = *(const bf16x8*)&lA[s2 + 1][r * 64 + (((ks * 4 + khi) ^ low7) << 3)];
            }
            if (stN) STG_B(0, tN, tp);
            BARRIER;
            __builtin_amdgcn_s_setprio(1);
#pragma unroll
            for (int fi = 0; fi < 4; ++fi)
#pragma unroll
                for (int fj = 0; fj < 2; ++fj)
#pragma unroll
                    for (int ks = 0; ks < 2; ++ks)
                        acc[4 + fi][2 + fj] = __builtin_amdgcn_mfma_f32_16x16x32_bf16(af[fi][ks], bf1[fj][ks], acc[4 + fi][2 + fj], 0, 0, 0);
            __builtin_amdgcn_s_setprio(0);
            WAITLGKM0;
            BARRIER;

            // ---- Pd: no reads (bf0 live); stage B-h1 of tile tN; counted vmcnt
            if (stN) STG_B(1, tN, tp);
            BARRIER;
            __builtin_amdgcn_s_setprio(1);
#pragma unroll
            for (int fi = 0; fi < 4; ++fi)
#pragma unroll
                for (int fj = 0; fj < 2; ++fj)
#pragma unroll
                    for (int ks = 0; ks < 2; ++ks)
                        acc[4 + fi][fj] = __builtin_amdgcn_mfma_f32_16x16x32_bf16(af[fi][ks], bf0[fj][ks], acc[4 + fi][fj], 0, 0, 0);
            __builtin_amdgcn_s_setprio(0);
            WAITVM6;     // all but newest 3 half-tiles landed (phases 4 & 8 only)
            WAITLGKM0;
            BARRIER;
        }
    }

    // ---- epilogue: C/D layout col=lane&15, row=(lane>>4)*4+r ----
    const int r4 = khi * 4;
#pragma unroll
    for (int jj = 0; jj < 4; ++jj) {
        const long col = col0 + (jj >> 1) * 128 + wn * 32 + (jj & 1) * 16 + arow;
        const float bj = bias[col];
#pragma unroll
        for (int i = 0; i < 8; ++i) {
            const long rowb = row0 + (i >> 2) * 128 + wm * 64 + (i & 3) * 16 + r4;
#pragma unroll
            for (int r = 0; r < 4; ++r) {
                const long row = rowb + r;
                float val = acc[i][jj][r] + bj;
                if (MODE == 2) {
                    float u = 1.5957691216057308f * (val + 0.044715f * val * val * val);
                    float e = __expf(u);
                    float th = 1.0f - 2.0f / (e + 1.0f);
                    val = 0.5f * val * (1.0f + th);
                }
                if (MODE == 1) {
                    ((float*)outv)[row * N + col] = res[row * N + col] + val;
                } else {
                    ((unsigned short*)outv)[row * N + col] = f2bf(val);
                }
            }
        }
    }
#undef STG_A
#undef STG_B
}

// ---------- MFMA attention: one block (256 thr, 4 waves) per (b,h); N=65 pad 80, D=64 ----------
// QK^T: 5x5 tiles of 16x16, K=64 (2 mfma). Softmax wave-parallel (4 lanes/row), P bf16
// unnormalized + per-row 1/sum applied in PV epilogue. PV: 5x4 tiles, K padded to 96 (3 mfma),
// V transposed in LDS (vt[d][j]); P cols 65..95 and vt cols 65..95 zeroed (no NaN leak).
// LDS strides 72/104/84 are bank-uniform for all frag reads. ss(f32) overlays q+k (dead after QK^T).
__global__ __launch_bounds__(256, 3) void attn_mfma(const unsigned short* __restrict__ qkv,
                                                    const float* __restrict__ abias,
                                                    const float* __restrict__ bscale_p,
                                                    unsigned short* __restrict__ o) {
    const int bh = blockIdx.x;
    const int b = bh >> 4, h = bh & 15;
    const int t = threadIdx.x;
    const int lane = t & 63;
    const int wave = t >> 6;

    __shared__ __align__(16) char smem[53252];
    unsigned short* lq = (unsigned short*)smem;             // [80][72] rows 65..79 uninit (ok)
    unsigned short* lk = (unsigned short*)(smem + 11520);   // [80][72]
    float* ss          = (float*)smem;                      // [65][84] overlays q+k after QK^T
    unsigned short* vt = (unsigned short*)(smem + 23040);   // [64][104]  V^T: vt[d][j]
    unsigned short* lp = (unsigned short*)(smem + 36352);   // [80][104]  P bf16 (unnormalized)
    float* sinv        = (float*)(smem + 52992);            // [65]

    // ---- stage q,k rows + transpose v; zero pads ----
    const size_t base = (size_t)b * 65 * 3072 + h * 64;
    for (int c = t; c < 520; c += 256) {
        const int row = c >> 3, s = c & 7;
        const size_t g = base + (size_t)row * 3072 + s * 8;
        *(ushort8*)&lq[row * 72 + s * 8] = *(const ushort8*)&qkv[g];
        *(ushort8*)&lk[row * 72 + s * 8] = *(const ushort8*)&qkv[g + 1024];
        ushort8 vv = *(const ushort8*)&qkv[g + 2048];
#pragma unroll
        for (int e = 0; e < 8; e++) vt[(s * 8 + e) * 104 + row] = vv[e];
    }
    for (int c = t; c < 2048; c += 256) vt[(c >> 5) * 104 + 65 + (c & 31)] = 0;  // d rows, j 65..96
    for (int c = t; c < 2080; c += 256) lp[(c >> 5) * 104 + 65 + (c & 31)] = 0;  // i rows 0..64
    __syncthreads();

    const int arow = lane & 15;
    const int khi8 = (lane >> 4) * 8;
    const int r4   = (lane >> 4) * 4;

    // ---- QK^T into regs (tiles tt = wave+4c over 5x5 grid) ----
    f32x4 acc[7];
#pragma unroll
    for (int c = 0; c < 7; c++) {
        const int tt = wave + 4 * c;
        if (tt < 25) {
            const int ti = tt / 5, tj = tt % 5;
            f32x4 a = {};
#pragma unroll
            for (int ks = 0; ks < 2; ks++) {
                bf16x8 af = *(const bf16x8*)&lq[(ti * 16 + arow) * 72 + khi8 + ks * 32];
                bf16x8 bf = *(const bf16x8*)&lk[(tj * 16 + arow) * 72 + khi8 + ks * 32];
                a = __builtin_amdgcn_mfma_f32_16x16x32_bf16(af, bf, a, 0, 0, 0);
            }
            acc[c] = a;
        }
    }
    __syncthreads();   // all q/k frag reads drained before ss overlays them

    // ---- scores -> ss (scale + bias), masked to valid rows ----
    const float bs = bscale_p[0];
    const float* bias_h = abias + h * 65 * 65;
#pragma unroll
    for (int c = 0; c < 7; c++) {
        const int tt = wave + 4 * c;
        if (tt < 25) {
            const int ti = tt / 5, tj = tt % 5;
            const int j = tj * 16 + arow;
            const int bj = j < 65 ? j : 64;          // clamp: stay in-bounds
#pragma unroll
            for (int r = 0; r < 4; r++) {
                const int i = ti * 16 + r4 + r;
                const int bi = i < 65 ? i : 64;
                const float val = acc[c][r] * 0.125f + bs * bias_h[bi * 65 + bj];
                if (i < 65) ss[i * 84 + j] = val;    // j<=79 < 84 always in-bounds
            }
        }
    }
    __syncthreads();

    // ---- softmax: 4 lanes per row, unnormalized bf16 P + 1/sum ----
    {
        const int l4 = t & 3;
        for (int r = t >> 2; r < 65; r += 64) {
            float m = -1e30f;
            for (int j = l4; j < 65; j += 4) m = fmaxf(m, ss[r * 84 + j]);
            m = fmaxf(m, __shfl_xor(m, 1, 64));
            m = fmaxf(m, __shfl_xor(m, 2, 64));
            float sum = 0.f;
            for (int j = l4; j < 65; j += 4) {
                const float e = __expf(ss[r * 84 + j] - m);
                lp[r * 104 + j] = f2bf(e);
                sum += e;
            }
            sum += __shfl_xor(sum, 1, 64);
            sum += __shfl_xor(sum, 2, 64);
            if (l4 == 0) sinv[r] = 1.0f / sum;
        }
    }
    __syncthreads();

    // ---- O = P @ V via vt[d][j]; wave owns d-column tj=wave, rows ti=c ----
#pragma unroll
    for (int c = 0; c < 5; c++) {
        const int ti = c, tj = wave;
        f32x4 a = {};
#pragma unroll
        for (int ks = 0; ks < 3; ks++) {
            bf16x8 pf = *(const bf16x8*)&lp[(ti * 16 + arow) * 104 + khi8 + ks * 32];
            bf16x8 vf = *(const bf16x8*)&vt[(tj * 16 + arow) * 104 + khi8 + ks * 32];
            a = __builtin_amdgcn_mfma_f32_16x16x32_bf16(pf, vf, a, 0, 0, 0);
        }
        const int d = tj * 16 + arow;
#pragma unroll
        for (int r = 0; r < 4; r++) {
            const int i = ti * 16 + r4 + r;
            if (i < 65)
                o[((size_t)(b * 65 + i)) * 1024 + h * 64 + d] = f2bf(a[r] * sinv[i]);
        }
    }
}

// ---------- driver ----------
extern "C" void kernel_launch(void* const* d_in, const int* in_sizes, int n_in,
                              void* d_out, int out_size, void* d_ws, size_t ws_size,
                              hipStream_t stream) {
    const float* x      = (const float*)d_in[0];
    const float* ln1_g  = (const float*)d_in[1];
    const float* ln1_b  = (const float*)d_in[2];
    const float* qkv_w  = (const float*)d_in[3];
    const float* qkv_b  = (const float*)d_in[4];
    const float* proj_w = (const float*)d_in[5];
    const float* proj_b = (const float*)d_in[6];
    const float* abias  = (const float*)d_in[7];
    const float* bscale = (const float*)d_in[8];
    const float* ln2_g  = (const float*)d_in[9];
    const float* ln2_b  = (const float*)d_in[10];
    const float* fc1_w  = (const float*)d_in[11];
    const float* fc1_b  = (const float*)d_in[12];
    const float* fc2_w  = (const float*)d_in[13];
    const float* fc2_b  = (const float*)d_in[14];
    float* out = (float*)d_out;

    char* ws = (char*)d_ws;
    unsigned short* qkvbuf = (unsigned short*)(ws);
    unsigned short* hbuf   = (unsigned short*)(ws + 545259520ULL);
    unsigned short* wqkv   = (unsigned short*)(ws + 681574400ULL);
    unsigned short* wproj  = (unsigned short*)(ws + 687865856ULL);
    unsigned short* wfc1   = (unsigned short*)(ws + 689963008ULL);
    unsigned short* wfc2   = (unsigned short*)(ws + 698351616ULL);

    const int M = 66560;  // B*N = 1024*65 = 260*256

    cvt_w<<<3072, 256, 0, stream>>>(qkv_w,  wqkv,  786432);
    cvt_w<<<1024, 256, 0, stream>>>(proj_w, wproj, 262144);
    cvt_w<<<4096, 256, 0, stream>>>(fc1_w,  wfc1,  1048576);
    cvt_w<<<4096, 256, 0, stream>>>(fc2_w,  wfc2,  1048576);

    ln_bf16<<<M, 256, 0, stream>>>(x, ln1_g, ln1_b, hbuf);                        // h1
    gemm8p<0><<<dim3(12, 260), 512, 0, stream>>>(hbuf, wqkv, qkv_b, nullptr,
                                                 (void*)qkvbuf, 3072, 1024);      // qkv
    attn_mfma<<<16384, 256, 0, stream>>>(qkvbuf, abias, bscale, hbuf);            // o
    gemm8p<1><<<dim3(4, 260), 512, 0, stream>>>(hbuf, wproj, proj_b, x,
                                                (void*)out, 1024, 1024);          // x2 = x + proj(o)
    ln_bf16<<<M, 256, 0, stream>>>(out, ln2_g, ln2_b, hbuf);                      // h2
    gemm8p<2><<<dim3(16, 260), 512, 0, stream>>>(hbuf, wfc1, fc1_b, nullptr,
                                                 (void*)qkvbuf, 4096, 1024);      // h3 = gelu(fc1)
    gemm8p<1><<<dim3(4, 260), 512, 0, stream>>>(qkvbuf, wfc2, fc2_b, out,
                                                (void*)out, 1024, 4096);          // out = x2 + fc2(h3)
}